// Round 14
// baseline (192.966 us; speedup 1.0000x reference)
//
#include <hip/hip_runtime.h>

#define D 64
#define ROWS 64
#define TPB 256
#define TPG 8   // contiguous tiles per block (dispatch-order L3 sweep)

typedef float f4 __attribute__((ext_vector_type(4)));
typedef short s8 __attribute__((ext_vector_type(8)));

static __device__ __forceinline__ unsigned short f2bf(float x) {
  union { float f; unsigned u; } v; v.f = x;
  return (unsigned short)((v.u + 0x7FFFu + ((v.u >> 16) & 1u)) >> 16);
}

static __device__ __forceinline__ s8 pack8(f4 a, f4 b) {
  s8 r;
  r[0] = (short)f2bf(a.x); r[1] = (short)f2bf(a.y);
  r[2] = (short)f2bf(a.z); r[3] = (short)f2bf(a.w);
  r[4] = (short)f2bf(b.x); r[5] = (short)f2bf(b.y);
  r[6] = (short)f2bf(b.z); r[7] = (short)f2bf(b.w);
  return r;
}

static __device__ __forceinline__ f4 fma4s(float a, f4 b, f4 c) {
  f4 r;
  r.x = fmaf(a, b.x, c.x);
  r.y = fmaf(a, b.y, c.y);
  r.z = fmaf(a, b.z, c.z);
  r.w = fmaf(a, b.w, c.w);
  return r;
}

static __device__ __forceinline__ f4 prelu4(f4 p, float a) {
  f4 r;
  r.x = p.x >= 0.0f ? p.x : a * p.x;
  r.y = p.y >= 0.0f ? p.y : a * p.y;
  r.z = p.z >= 0.0f ? p.z : a * p.z;
  r.w = p.w >= 0.0f ? p.w : a * p.w;
  return r;
}

static __device__ __forceinline__ float dot4(f4 x, f4 y, f4 z, float acc) {
  acc = fmaf(x.x + y.x, z.x, acc);
  acc = fmaf(x.y + y.y, z.y, acc);
  acc = fmaf(x.z + y.z, z.z, acc);
  acc = fmaf(x.w + y.w, z.w, acc);
  return acc;
}

static __device__ __forceinline__ f4 shfl4(f4 v, int src) {
  f4 r;
  r.x = __shfl(v.x, src);
  r.y = __shfl(v.y, src);
  r.z = __shfl(v.z, src);
  r.w = __shfl(v.w, src);
  return r;
}

// R14 = R13's loop with LOCAL tile groups. R13's persistent grid-strided
// sweep (768 concurrent fronts over 256MB) thrashed L3: FETCH 355MB vs
// R10's 133MB (dispatch-order sweep, ~50% L3 hit since h+keys ~= L3 size).
// Now each block does TPG=8 CONTIGUOUS tiles, grid = ntiles/8 in dispatch
// order: compact sweep front (L3 locality of R10) + within-block prefetch
// pipeline (BW of R13, 7/8 coverage). Loop body unchanged: 8-f4 bundle
// (84 VGPR, proven), hr via quad shuffles, zero mid-loop global reads.
__global__ __launch_bounds__(TPB, 3) void dmc_fused(
    const float* __restrict__ h,
    const float* __restrict__ keys,
    const float* __restrict__ s,
    const float* __restrict__ U,
    const float* __restrict__ V,
    const float* __restrict__ W,
    const float* __restrict__ bias,
    const float* __restrict__ prelu_a,
    float* __restrict__ out,
    const int nblocks,
    const int ntiles) {
  __shared__ __align__(16) unsigned short Ub[D * D];  // 8KB bf16, swizzled
  __shared__ __align__(16) unsigned short Vb[D * D];  // 8KB
  __shared__ __align__(16) float cc[D];

  const int tid  = threadIdx.x;
  const int lane = tid & 63;
  const int wv   = tid >> 6;            // 0..3 = batch row-block
  const int g    = lane >> 4;           // 0..3
  const int rl   = lane & 15;           // MFMA n (batch row) / m (U row)
  const int r    = wv * 16 + rl;        // batch row within a tile

  // ---- stage U, V -> bf16 LDS [c][64k], 16B chunk sl at phys = sl^(c&7) ----
  const f4* __restrict__ Ug = reinterpret_cast<const f4*>(U);
  const f4* __restrict__ Vg = reinterpret_cast<const f4*>(V);
  s8* __restrict__ Ub8w = reinterpret_cast<s8*>(Ub);
  s8* __restrict__ Vb8w = reinterpret_cast<s8*>(Vb);
  #pragma unroll
  for (int t = 0; t < 2; ++t) {
    const int m  = tid + TPB * t;       // 0..511 chunk id
    const int c  = m >> 3;
    const int sl = m & 7;
    Ub8w[c * 8 + (sl ^ (c & 7))] = pack8(Ug[c * 16 + sl * 2], Ug[c * 16 + sl * 2 + 1]);
    Vb8w[c * 8 + (sl ^ (c & 7))] = pack8(Vg[c * 16 + sl * 2], Vg[c * 16 + sl * 2 + 1]);
  }

  // ---- cc[c] = bias[c] + W[c,:] @ s ----
  if (tid < D) {
    const f4* __restrict__ wr = reinterpret_cast<const f4*>(W + tid * D);
    const f4* __restrict__ sr = reinterpret_cast<const f4*>(s);
    float acc = bias[tid];
    #pragma unroll
    for (int q = 0; q < 16; ++q) {
      const f4 wq = wr[q];
      const f4 sq = sr[q];
      acc = fmaf(wq.x, sq.x, acc);
      acc = fmaf(wq.y, sq.y, acc);
      acc = fmaf(wq.z, sq.z, acc);
      acc = fmaf(wq.w, sq.w, acc);
    }
    cc[tid] = acc;
  }

  // ---- hoist s chunks + prelu a ----
  const f4* __restrict__ sg4 = reinterpret_cast<const f4*>(s);
  const f4 sA0 = sg4[2 * g];
  const f4 sA1 = sg4[2 * g + 1];
  const f4 sB0 = sg4[8 + 2 * g];
  const f4 sB1 = sg4[8 + 2 * g + 1];
  const float a = prelu_a[0];

  // shuffle source lanes (quad = same row, 4 g's)
  const int srcA = ((g >> 1) << 4) + rl;
  const int srcB = srcA + 32;

  // ---- tile group [tstart, tend) ----
  int tt = blockIdx.x * TPG;
  const int tend = (tt + TPG < ntiles) ? (tt + TPG) : ntiles;

  // ---- prefetch first tile's B-fragments ----
  f4 ph0a, ph0b, ph1a, ph1b, pk0a, pk0b, pk1a, pk1b;
  {
    const int j0 = tt * ROWS;
    const int nrem = nblocks - j0;
    const int rc = (r < nrem) ? r : (nrem - 1);
    const f4* __restrict__ hrow = reinterpret_cast<const f4*>(h + (size_t)(j0 + rc) * D);
    const f4* __restrict__ krow = reinterpret_cast<const f4*>(keys + (size_t)(j0 + rc) * D);
    ph0a = hrow[2 * g];     ph0b = hrow[2 * g + 1];
    ph1a = hrow[8 + 2 * g]; ph1b = hrow[8 + 2 * g + 1];
    pk0a = krow[2 * g];     pk0b = krow[2 * g + 1];
    pk1a = krow[8 + 2 * g]; pk1b = krow[8 + 2 * g + 1];
  }

  __syncthreads();

  const s8* __restrict__ Ub8 = reinterpret_cast<const s8*>(Ub);
  const s8* __restrict__ Vb8 = reinterpret_cast<const s8*>(Vb);
  const f4* __restrict__ cc4 = reinterpret_cast<const f4*>(cc);
  // A-frag LDS indices (loop-invariant): c = cb*16+rl, slot = (ks*4+g)^(rl&7)
  const int xr = rl & 7;
  const int iu0 = (rl) * 8,      iu1 = (16 + rl) * 8;
  const int iu2 = (32 + rl) * 8, iu3 = (48 + rl) * 8;
  const int slA = (0 + g) ^ xr;  // ks = 0
  const int slB = (4 + g) ^ xr;  // ks = 1

  // ---- tile loop: zero mid-loop global reads; prefetch covers 7/8 ----
  while (tt < tend) {
    const int ct = tt;
    ++tt;
    const int j0   = ct * ROWS;
    const int nrem = nblocks - j0;

    // gate partials + packs (consume ph/pk)
    float gd = dot4(ph0a, pk0a, sA0, 0.0f);
    gd = dot4(ph0b, pk0b, sA1, gd);
    gd = dot4(ph1a, pk1a, sB0, gd);
    gd = dot4(ph1b, pk1b, sB1, gd);
    const s8 bh0 = pack8(ph0a, ph0b);
    const s8 bh1 = pack8(ph1a, ph1b);
    const s8 bk0 = pack8(pk0a, pk0b);
    const s8 bk1 = pack8(pk1a, pk1b);

    // hr in D-frag layout via quad shuffles (consumes ph; no global read)
    const int odd = g & 1;
    const f4 A0 = shfl4(ph0a, srcA), B0 = shfl4(ph0b, srcA);
    const f4 A1 = shfl4(ph0a, srcB), B1 = shfl4(ph0b, srcB);
    const f4 A2 = shfl4(ph1a, srcA), B2 = shfl4(ph1b, srcA);
    const f4 A3 = shfl4(ph1a, srcB), B3 = shfl4(ph1b, srcB);
    const f4 hr0 = odd ? B0 : A0;
    const f4 hr1 = odd ? B1 : A1;
    const f4 hr2 = odd ? B2 : A2;
    const f4 hr3 = odd ? B3 : A3;

    // prefetch NEXT (contiguous) tile — stays outstanding through MFMA
    if (tt < tend) {
      const int j0n = tt * ROWS;
      const int nremn = nblocks - j0n;
      const int rcn = (r < nremn) ? r : (nremn - 1);
      const f4* __restrict__ hrn = reinterpret_cast<const f4*>(h + (size_t)(j0n + rcn) * D);
      const f4* __restrict__ krn = reinterpret_cast<const f4*>(keys + (size_t)(j0n + rcn) * D);
      ph0a = hrn[2 * g];     ph0b = hrn[2 * g + 1];
      ph1a = hrn[8 + 2 * g]; ph1b = hrn[8 + 2 * g + 1];
      pk0a = krn[2 * g];     pk0b = krn[2 * g + 1];
      pk1a = krn[8 + 2 * g]; pk1b = krn[8 + 2 * g + 1];
    }

    // MFMA: K=64 as 2 slices of 32 (A-frags from conflict-free swizzled LDS)
    f4 a0 = cc4[0 + g], a1 = cc4[4 + g], a2 = cc4[8 + g], a3 = cc4[12 + g];
    a0 = __builtin_amdgcn_mfma_f32_16x16x32_bf16(Ub8[iu0 + slA], bh0, a0, 0, 0, 0);
    a1 = __builtin_amdgcn_mfma_f32_16x16x32_bf16(Ub8[iu1 + slA], bh0, a1, 0, 0, 0);
    a2 = __builtin_amdgcn_mfma_f32_16x16x32_bf16(Ub8[iu2 + slA], bh0, a2, 0, 0, 0);
    a3 = __builtin_amdgcn_mfma_f32_16x16x32_bf16(Ub8[iu3 + slA], bh0, a3, 0, 0, 0);
    a0 = __builtin_amdgcn_mfma_f32_16x16x32_bf16(Vb8[iu0 + slA], bk0, a0, 0, 0, 0);
    a1 = __builtin_amdgcn_mfma_f32_16x16x32_bf16(Vb8[iu1 + slA], bk0, a1, 0, 0, 0);
    a2 = __builtin_amdgcn_mfma_f32_16x16x32_bf16(Vb8[iu2 + slA], bk0, a2, 0, 0, 0);
    a3 = __builtin_amdgcn_mfma_f32_16x16x32_bf16(Vb8[iu3 + slA], bk0, a3, 0, 0, 0);
    a0 = __builtin_amdgcn_mfma_f32_16x16x32_bf16(Ub8[iu0 + slB], bh1, a0, 0, 0, 0);
    a1 = __builtin_amdgcn_mfma_f32_16x16x32_bf16(Ub8[iu1 + slB], bh1, a1, 0, 0, 0);
    a2 = __builtin_amdgcn_mfma_f32_16x16x32_bf16(Ub8[iu2 + slB], bh1, a2, 0, 0, 0);
    a3 = __builtin_amdgcn_mfma_f32_16x16x32_bf16(Ub8[iu3 + slB], bh1, a3, 0, 0, 0);
    a0 = __builtin_amdgcn_mfma_f32_16x16x32_bf16(Vb8[iu0 + slB], bk1, a0, 0, 0, 0);
    a1 = __builtin_amdgcn_mfma_f32_16x16x32_bf16(Vb8[iu1 + slB], bk1, a1, 0, 0, 0);
    a2 = __builtin_amdgcn_mfma_f32_16x16x32_bf16(Vb8[iu2 + slB], bk1, a2, 0, 0, 0);
    a3 = __builtin_amdgcn_mfma_f32_16x16x32_bf16(Vb8[iu3 + slB], bk1, a3, 0, 0, 0);

    // gate reduce (g-lanes hold disjoint k-ranges), sigmoid
    gd += __shfl_xor(gd, 16);
    gd += __shfl_xor(gd, 32);
    const float gt = 1.0f / (1.0f + __expf(-gd));

    // gated residual + row norm
    f4 o0 = fma4s(gt, prelu4(a0, a), hr0);
    f4 o1 = fma4s(gt, prelu4(a1, a), hr1);
    f4 o2 = fma4s(gt, prelu4(a2, a), hr2);
    f4 o3 = fma4s(gt, prelu4(a3, a), hr3);

    float ss = o0.x * o0.x + o0.y * o0.y + o0.z * o0.z + o0.w * o0.w;
    ss = fmaf(o1.x, o1.x, ss); ss = fmaf(o1.y, o1.y, ss);
    ss = fmaf(o1.z, o1.z, ss); ss = fmaf(o1.w, o1.w, ss);
    ss = fmaf(o2.x, o2.x, ss); ss = fmaf(o2.y, o2.y, ss);
    ss = fmaf(o2.z, o2.z, ss); ss = fmaf(o2.w, o2.w, ss);
    ss = fmaf(o3.x, o3.x, ss); ss = fmaf(o3.y, o3.y, ss);
    ss = fmaf(o3.z, o3.z, ss); ss = fmaf(o3.w, o3.w, ss);
    ss += __shfl_xor(ss, 16);
    ss += __shfl_xor(ss, 32);
    const float rn = rsqrtf(ss);

    if (r < nrem) {
      float* __restrict__ orow = out + (size_t)(j0 + r) * D + g * 4;
      *reinterpret_cast<f4*>(orow +  0) = o0 * rn;
      *reinterpret_cast<f4*>(orow + 16) = o1 * rn;
      *reinterpret_cast<f4*>(orow + 32) = o2 * rn;
      *reinterpret_cast<f4*>(orow + 48) = o3 * rn;
    }
  }
}

extern "C" void kernel_launch(void* const* d_in, const int* in_sizes, int n_in,
                              void* d_out, int out_size, void* d_ws, size_t ws_size,
                              hipStream_t stream) {
  const float* s       = (const float*)d_in[0];
  const float* h       = (const float*)d_in[1];
  const float* keys    = (const float*)d_in[2];
  const float* U       = (const float*)d_in[3];
  const float* V       = (const float*)d_in[4];
  const float* W       = (const float*)d_in[5];
  const float* bias    = (const float*)d_in[6];
  const float* prelu_a = (const float*)d_in[7];
  float* out = (float*)d_out;

  const int nblocks = in_sizes[1] / D;
  const int ntiles  = (nblocks + ROWS - 1) / ROWS;
  const int grid    = (ntiles + TPG - 1) / TPG;
  dmc_fused<<<grid, TPB, 0, stream>>>(h, keys, s, U, V, W, bias, prelu_a, out,
                                      nblocks, ntiles);
}

// Round 15
// 103.138 us; speedup vs baseline: 1.8710x; 1.8710x over previous
//
#include <hip/hip_runtime.h>

#define D 64
#define ROWS 64
#define TPB 256

typedef float f4 __attribute__((ext_vector_type(4)));
typedef short s8 __attribute__((ext_vector_type(8)));

static __device__ __forceinline__ unsigned short f2bf(float x) {
  union { float f; unsigned u; } v; v.f = x;
  return (unsigned short)((v.u + 0x7FFFu + ((v.u >> 16) & 1u)) >> 16);
}

static __device__ __forceinline__ s8 pack8(f4 a, f4 b) {
  s8 r;
  r[0] = (short)f2bf(a.x); r[1] = (short)f2bf(a.y);
  r[2] = (short)f2bf(a.z); r[3] = (short)f2bf(a.w);
  r[4] = (short)f2bf(b.x); r[5] = (short)f2bf(b.y);
  r[6] = (short)f2bf(b.z); r[7] = (short)f2bf(b.w);
  return r;
}

static __device__ __forceinline__ f4 fma4s(float a, f4 b, f4 c) {
  f4 r;
  r.x = fmaf(a, b.x, c.x);
  r.y = fmaf(a, b.y, c.y);
  r.z = fmaf(a, b.z, c.z);
  r.w = fmaf(a, b.w, c.w);
  return r;
}

static __device__ __forceinline__ f4 prelu4(f4 p, float a) {
  f4 r;
  r.x = p.x >= 0.0f ? p.x : a * p.x;
  r.y = p.y >= 0.0f ? p.y : a * p.y;
  r.z = p.z >= 0.0f ? p.z : a * p.z;
  r.w = p.w >= 0.0f ? p.w : a * p.w;
  return r;
}

static __device__ __forceinline__ float dot4(f4 x, f4 y, f4 z, float acc) {
  acc = fmaf(x.x + y.x, z.x, acc);
  acc = fmaf(x.y + y.y, z.y, acc);
  acc = fmaf(x.z + y.z, z.z, acc);
  acc = fmaf(x.w + y.w, z.w, acc);
  return acc;
}

// R15 = R10 (best minimal-traffic structure: dispatch-ordered single-tile
// blocks, 384MB total demand) with FORCED deep per-wave MLP. R10's VGPR=36
// shows the compiler serialized its 12 loads (reused dest regs, shallow
// vmcnt windows) -> per-block critical path paid most of the load latency
// after the staging barrier. Here: issue ALL 12 f4 loads FIRST, pin with
// sched_barrier(0), then do U/V/cc LDS staging + __syncthreads WHILE they
// are in flight, then consume. Single-tile block = no loop-carried bundle =
// no R12-style demotion. Everything else byte-identical to R10.
__global__ __launch_bounds__(TPB, 4) void dmc_fused(
    const float* __restrict__ h,
    const float* __restrict__ keys,
    const float* __restrict__ s,
    const float* __restrict__ U,
    const float* __restrict__ V,
    const float* __restrict__ W,
    const float* __restrict__ bias,
    const float* __restrict__ prelu_a,
    float* __restrict__ out,
    const int nblocks) {
  __shared__ __align__(16) unsigned short Ub[D * D];  // 8KB bf16, swizzled
  __shared__ __align__(16) unsigned short Vb[D * D];  // 8KB
  __shared__ __align__(16) float cc[D];

  const int tid  = threadIdx.x;
  const int lane = tid & 63;
  const int wv   = tid >> 6;            // 0..3 = batch row-block
  const int g    = lane >> 4;           // 0..3
  const int rl   = lane & 15;           // MFMA n (batch row) / m (U row)
  const int r    = wv * 16 + rl;        // batch row within tile
  const int j0   = blockIdx.x * ROWS;
  const int nrem = nblocks - j0;
  const int rc   = (r < nrem) ? r : (nrem - 1);

  // ---- 1) issue ALL per-lane global loads first (12 f4 = 48 VGPR dest) ----
  const f4* __restrict__ hrow = reinterpret_cast<const f4*>(h + (size_t)(j0 + rc) * D);
  const f4* __restrict__ krow = reinterpret_cast<const f4*>(keys + (size_t)(j0 + rc) * D);
  const f4 ph0a = hrow[2 * g];      const f4 ph0b = hrow[2 * g + 1];
  const f4 ph1a = hrow[8 + 2 * g];  const f4 ph1b = hrow[8 + 2 * g + 1];
  const f4 pk0a = krow[2 * g];      const f4 pk0b = krow[2 * g + 1];
  const f4 pk1a = krow[8 + 2 * g];  const f4 pk1b = krow[8 + 2 * g + 1];
  const f4 hr0 = hrow[0 + g];
  const f4 hr1 = hrow[4 + g];
  const f4 hr2 = hrow[8 + g];
  const f4 hr3 = hrow[12 + g];
  // Pin: nothing below may be hoisted above these loads; loads stay issued.
  __builtin_amdgcn_sched_barrier(0);

  // ---- 2) stage U, V -> bf16 LDS (overlaps the in-flight loads) ----
  const f4* __restrict__ Ug = reinterpret_cast<const f4*>(U);
  const f4* __restrict__ Vg = reinterpret_cast<const f4*>(V);
  s8* __restrict__ Ub8w = reinterpret_cast<s8*>(Ub);
  s8* __restrict__ Vb8w = reinterpret_cast<s8*>(Vb);
  #pragma unroll
  for (int t = 0; t < 2; ++t) {
    const int m  = tid + TPB * t;       // 0..511 chunk id
    const int c  = m >> 3;
    const int sl = m & 7;
    Ub8w[c * 8 + (sl ^ (c & 7))] = pack8(Ug[c * 16 + sl * 2], Ug[c * 16 + sl * 2 + 1]);
    Vb8w[c * 8 + (sl ^ (c & 7))] = pack8(Vg[c * 16 + sl * 2], Vg[c * 16 + sl * 2 + 1]);
  }

  // ---- cc[c] = bias[c] + W[c,:] @ s ----
  if (tid < D) {
    const f4* __restrict__ wr = reinterpret_cast<const f4*>(W + tid * D);
    const f4* __restrict__ sr = reinterpret_cast<const f4*>(s);
    float acc = bias[tid];
    #pragma unroll
    for (int q = 0; q < 16; ++q) {
      const f4 wq = wr[q];
      const f4 sq = sr[q];
      acc = fmaf(wq.x, sq.x, acc);
      acc = fmaf(wq.y, sq.y, acc);
      acc = fmaf(wq.z, sq.z, acc);
      acc = fmaf(wq.w, sq.w, acc);
    }
    cc[tid] = acc;
  }
  __syncthreads();

  // ---- 3) consume: gate dot (f32, pre-pack) + B-frag packs ----
  const f4* __restrict__ sg4 = reinterpret_cast<const f4*>(s);
  float gd = dot4(ph0a, pk0a, sg4[2 * g], 0.0f);
  gd = dot4(ph0b, pk0b, sg4[2 * g + 1], gd);
  gd = dot4(ph1a, pk1a, sg4[8 + 2 * g], gd);
  gd = dot4(ph1b, pk1b, sg4[8 + 2 * g + 1], gd);
  const s8 bh0 = pack8(ph0a, ph0b);
  const s8 bh1 = pack8(ph1a, ph1b);
  const s8 bk0 = pack8(pk0a, pk0b);
  const s8 bk1 = pack8(pk1a, pk1b);

  // ---- accumulators from cc ----
  const f4* __restrict__ cc4 = reinterpret_cast<const f4*>(cc);
  f4 acc0 = cc4[0 + g];
  f4 acc1 = cc4[4 + g];
  f4 acc2 = cc4[8 + g];
  f4 acc3 = cc4[12 + g];

  // ---- MFMA: K=64 as 2 slices of 32 (A-frags from swizzled LDS) ----
  const s8* __restrict__ Ub8 = reinterpret_cast<const s8*>(Ub);
  const s8* __restrict__ Vb8 = reinterpret_cast<const s8*>(Vb);
  #pragma unroll
  for (int ks = 0; ks < 2; ++ks) {
    const int asl = ks * 4 + g;
    const s8 bh = (ks == 0) ? bh0 : bh1;
    const s8 bk = (ks == 0) ? bk0 : bk1;
    const int c0i = 0 * 16 + rl, c1i = 1 * 16 + rl;
    const int c2i = 2 * 16 + rl, c3i = 3 * 16 + rl;
    const s8 au0 = Ub8[c0i * 8 + (asl ^ (c0i & 7))];
    const s8 au1 = Ub8[c1i * 8 + (asl ^ (c1i & 7))];
    const s8 au2 = Ub8[c2i * 8 + (asl ^ (c2i & 7))];
    const s8 au3 = Ub8[c3i * 8 + (asl ^ (c3i & 7))];
    const s8 av0 = Vb8[c0i * 8 + (asl ^ (c0i & 7))];
    const s8 av1 = Vb8[c1i * 8 + (asl ^ (c1i & 7))];
    const s8 av2 = Vb8[c2i * 8 + (asl ^ (c2i & 7))];
    const s8 av3 = Vb8[c3i * 8 + (asl ^ (c3i & 7))];
    acc0 = __builtin_amdgcn_mfma_f32_16x16x32_bf16(au0, bh, acc0, 0, 0, 0);
    acc1 = __builtin_amdgcn_mfma_f32_16x16x32_bf16(au1, bh, acc1, 0, 0, 0);
    acc2 = __builtin_amdgcn_mfma_f32_16x16x32_bf16(au2, bh, acc2, 0, 0, 0);
    acc3 = __builtin_amdgcn_mfma_f32_16x16x32_bf16(au3, bh, acc3, 0, 0, 0);
    acc0 = __builtin_amdgcn_mfma_f32_16x16x32_bf16(av0, bk, acc0, 0, 0, 0);
    acc1 = __builtin_amdgcn_mfma_f32_16x16x32_bf16(av1, bk, acc1, 0, 0, 0);
    acc2 = __builtin_amdgcn_mfma_f32_16x16x32_bf16(av2, bk, acc2, 0, 0, 0);
    acc3 = __builtin_amdgcn_mfma_f32_16x16x32_bf16(av3, bk, acc3, 0, 0, 0);
  }

  // ---- gate reduce (lanes of equal rl hold disjoint k-ranges) ----
  gd += __shfl_xor(gd, 16);
  gd += __shfl_xor(gd, 32);
  const float gt = 1.0f / (1.0f + __expf(-gd));
  const float a  = prelu_a[0];

  // ---- gated residual + row norm ----
  f4 o0 = fma4s(gt, prelu4(acc0, a), hr0);
  f4 o1 = fma4s(gt, prelu4(acc1, a), hr1);
  f4 o2 = fma4s(gt, prelu4(acc2, a), hr2);
  f4 o3 = fma4s(gt, prelu4(acc3, a), hr3);

  float ss = o0.x * o0.x + o0.y * o0.y + o0.z * o0.z + o0.w * o0.w;
  ss = fmaf(o1.x, o1.x, ss); ss = fmaf(o1.y, o1.y, ss);
  ss = fmaf(o1.z, o1.z, ss); ss = fmaf(o1.w, o1.w, ss);
  ss = fmaf(o2.x, o2.x, ss); ss = fmaf(o2.y, o2.y, ss);
  ss = fmaf(o2.z, o2.z, ss); ss = fmaf(o2.w, o2.w, ss);
  ss = fmaf(o3.x, o3.x, ss); ss = fmaf(o3.y, o3.y, ss);
  ss = fmaf(o3.z, o3.z, ss); ss = fmaf(o3.w, o3.w, ss);
  ss += __shfl_xor(ss, 16);
  ss += __shfl_xor(ss, 32);
  const float rn = rsqrtf(ss);

  if (r < nrem) {
    float* __restrict__ orow = out + (size_t)(j0 + r) * D + g * 4;
    *reinterpret_cast<f4*>(orow +  0) = o0 * rn;
    *reinterpret_cast<f4*>(orow + 16) = o1 * rn;
    *reinterpret_cast<f4*>(orow + 32) = o2 * rn;
    *reinterpret_cast<f4*>(orow + 48) = o3 * rn;
  }
}

extern "C" void kernel_launch(void* const* d_in, const int* in_sizes, int n_in,
                              void* d_out, int out_size, void* d_ws, size_t ws_size,
                              hipStream_t stream) {
  const float* s       = (const float*)d_in[0];
  const float* h       = (const float*)d_in[1];
  const float* keys    = (const float*)d_in[2];
  const float* U       = (const float*)d_in[3];
  const float* V       = (const float*)d_in[4];
  const float* W       = (const float*)d_in[5];
  const float* bias    = (const float*)d_in[6];
  const float* prelu_a = (const float*)d_in[7];
  float* out = (float*)d_out;

  const int nblocks = in_sizes[1] / D;
  const int grid = (nblocks + ROWS - 1) / ROWS;
  dmc_fused<<<grid, TPB, 0, stream>>>(h, keys, s, U, V, W, bias, prelu_a, out,
                                      nblocks);
}